// Round 3
// baseline (1172.835 us; speedup 1.0000x reference)
//
#include <hip/hip_runtime.h>

// ---------------------------------------------------------------------------
// ConstraintLoss:
//   values = sigmoid(pred)                                  [n_vars]   (bf16)
//   ax = segment_sum(coeff * values[var_idx], constr_idx)   [n_constrs]
//        -> K replicated accumulators to spread atomic contention
//   viol[c] = sense==1 ? relu(ax-b) : sense==2 ? relu(b-ax) : |ax-b|
//   out = mean(viol)
// ---------------------------------------------------------------------------

typedef int   i4 __attribute__((ext_vector_type(4)));
typedef float f4 __attribute__((ext_vector_type(4)));

__device__ __forceinline__ float bf16_to_f32(unsigned short u) {
    union { unsigned int i; float f; } cvt;
    cvt.i = ((unsigned int)u) << 16;
    return cvt.f;
}

__device__ __forceinline__ unsigned short f32_to_bf16_rne(float f) {
    union { float f; unsigned int i; } cvt;
    cvt.f = f;
    unsigned int u = cvt.i;
    u += 0x7FFFu + ((u >> 16) & 1u);  // round to nearest even
    return (unsigned short)(u >> 16);
}

__global__ void sigmoid_kernel(const float* __restrict__ pred,
                               unsigned short* __restrict__ values, int n) {
    int i = blockIdx.x * blockDim.x + threadIdx.x;
    int stride = gridDim.x * blockDim.x;
    int n4 = n >> 2;
    const f4* p4 = (const f4*)pred;
    for (int j = i; j < n4; j += stride) {
        f4 p = p4[j];
        ushort4 o;
        o.x = f32_to_bf16_rne(1.0f / (1.0f + __expf(-p.x)));
        o.y = f32_to_bf16_rne(1.0f / (1.0f + __expf(-p.y)));
        o.z = f32_to_bf16_rne(1.0f / (1.0f + __expf(-p.z)));
        o.w = f32_to_bf16_rne(1.0f / (1.0f + __expf(-p.w)));
        ((ushort4*)values)[j] = o;
    }
    for (int j = (n4 << 2) + i; j < n; j += stride)
        values[j] = f32_to_bf16_rne(1.0f / (1.0f + __expf(-pred[j])));
}

__global__ void scatter_kernel(const int* __restrict__ cidx,
                               const int* __restrict__ vidx,
                               const float* __restrict__ coeff,
                               const unsigned short* __restrict__ values,
                               float* __restrict__ ax, int nnz,
                               int n_constrs, int kmask) {
    int i = blockIdx.x * blockDim.x + threadIdx.x;
    int stride = gridDim.x * blockDim.x;
    int n4 = nnz >> 2;
    const i4* c4 = (const i4*)cidx;
    const i4* v4 = (const i4*)vidx;
    const f4* w4 = (const f4*)coeff;
    // each block accumulates into one of K replicas -> K x fewer atomics/line
    float* axr = ax + (size_t)(blockIdx.x & kmask) * (size_t)n_constrs;
    for (int j = i; j < n4; j += stride) {
        // non-temporal: don't let the 240 MB streams evict the values table
        i4 c = __builtin_nontemporal_load(&c4[j]);
        i4 v = __builtin_nontemporal_load(&v4[j]);
        f4 w = __builtin_nontemporal_load(&w4[j]);
        atomicAdd(&axr[c.x], w.x * bf16_to_f32(values[v.x]));
        atomicAdd(&axr[c.y], w.y * bf16_to_f32(values[v.y]));
        atomicAdd(&axr[c.z], w.z * bf16_to_f32(values[v.z]));
        atomicAdd(&axr[c.w], w.w * bf16_to_f32(values[v.w]));
    }
    for (int j = (n4 << 2) + i; j < nnz; j += stride)
        atomicAdd(&axr[cidx[j]], coeff[j] * bf16_to_f32(values[vidx[j]]));
}

__global__ void combine_reduce_kernel(const float* __restrict__ ax,
                                      const float* __restrict__ rhs,
                                      const int* __restrict__ sense,
                                      float* __restrict__ out,
                                      int n, int nrep, float inv_n) {
    int i = blockIdx.x * blockDim.x + threadIdx.x;
    int stride = gridDim.x * blockDim.x;
    float acc = 0.0f;
    int n4 = n >> 2;
    const f4* r4 = (const f4*)rhs;
    const i4* s4 = (const i4*)sense;
    for (int j = i; j < n4; j += stride) {
        f4 a = ((const f4*)ax)[j];
        for (int r = 1; r < nrep; ++r) {
            f4 b = ((const f4*)(ax + (size_t)r * (size_t)n))[j];
            a.x += b.x; a.y += b.y; a.z += b.z; a.w += b.w;
        }
        f4 rr = r4[j];
        i4 s = s4[j];
        float d;
        d = a.x - rr.x;
        acc += (s.x == 1) ? fmaxf(d, 0.0f) : (s.x == 2) ? fmaxf(-d, 0.0f) : (s.x == 3) ? fabsf(d) : 0.0f;
        d = a.y - rr.y;
        acc += (s.y == 1) ? fmaxf(d, 0.0f) : (s.y == 2) ? fmaxf(-d, 0.0f) : (s.y == 3) ? fabsf(d) : 0.0f;
        d = a.z - rr.z;
        acc += (s.z == 1) ? fmaxf(d, 0.0f) : (s.z == 2) ? fmaxf(-d, 0.0f) : (s.z == 3) ? fabsf(d) : 0.0f;
        d = a.w - rr.w;
        acc += (s.w == 1) ? fmaxf(d, 0.0f) : (s.w == 2) ? fmaxf(-d, 0.0f) : (s.w == 3) ? fabsf(d) : 0.0f;
    }
    for (int j = (n4 << 2) + i; j < n; j += stride) {
        float a = 0.0f;
        for (int r = 0; r < nrep; ++r) a += ax[(size_t)r * (size_t)n + j];
        float d = a - rhs[j];
        int s = sense[j];
        acc += (s == 1) ? fmaxf(d, 0.0f) : (s == 2) ? fmaxf(-d, 0.0f) : (s == 3) ? fabsf(d) : 0.0f;
    }

    for (int off = 32; off > 0; off >>= 1)
        acc += __shfl_down(acc, off, 64);

    __shared__ float lds[8];
    int lane = threadIdx.x & 63;
    int wave = threadIdx.x >> 6;
    if (lane == 0) lds[wave] = acc;
    __syncthreads();
    if (wave == 0) {
        int nwaves = blockDim.x >> 6;
        float b = (lane < nwaves) ? lds[lane] : 0.0f;
        for (int off = 4; off > 0; off >>= 1)
            b += __shfl_down(b, off, 64);
        if (lane == 0) atomicAdd(out, b * inv_n);
    }
}

extern "C" void kernel_launch(void* const* d_in, const int* in_sizes, int n_in,
                              void* d_out, int out_size, void* d_ws, size_t ws_size,
                              hipStream_t stream) {
    const float* pred  = (const float*)d_in[0];
    const int*   cidx  = (const int*)d_in[1];
    const int*   vidx  = (const int*)d_in[2];
    const float* coeff = (const float*)d_in[3];
    const float* rhs   = (const float*)d_in[4];
    const int*   sense = (const int*)d_in[5];

    const int n_vars    = in_sizes[0];
    const int nnz       = in_sizes[1];
    const int n_constrs = in_sizes[4];

    // workspace layout: values (bf16, n_vars) | ax replicas (K * n_constrs f32)
    unsigned short* values = (unsigned short*)d_ws;
    size_t values_bytes = ((size_t)n_vars * 2 + 255) & ~(size_t)255;
    float* ax = (float*)((char*)d_ws + values_bytes);

    // pick K = largest power of two <= 8 that fits in the workspace
    int K = 8;
    while (K > 1 && values_bytes + (size_t)K * n_constrs * sizeof(float) > ws_size)
        K >>= 1;

    (void)hipMemsetAsync(ax, 0, (size_t)K * n_constrs * sizeof(float), stream);
    (void)hipMemsetAsync(d_out, 0, sizeof(float), stream);

    {
        int threads = 256;
        int blocks = ((n_vars >> 2) + threads - 1) / threads;
        sigmoid_kernel<<<blocks, threads, 0, stream>>>(pred, values, n_vars);
    }
    {
        int threads = 256;
        int blocks = 8192;
        scatter_kernel<<<blocks, threads, 0, stream>>>(cidx, vidx, coeff, values,
                                                       ax, nnz, n_constrs, K - 1);
    }
    {
        int threads = 256;
        int blocks = ((n_constrs >> 2) + threads - 1) / threads;
        if (blocks > 4096) blocks = 4096;
        combine_reduce_kernel<<<blocks, threads, 0, stream>>>(
            ax, rhs, sense, (float*)d_out, n_constrs, K, 1.0f / (float)n_constrs);
    }
}

// Round 5
// 1172.320 us; speedup vs baseline: 1.0004x; 1.0004x over previous
//
#include <hip/hip_runtime.h>

// ---------------------------------------------------------------------------
// ConstraintLoss:
//   values = sigmoid(pred)                                  [n_vars]   (bf16)
//   ax = segment_sum(coeff * values[var_idx], constr_idx)   [n_constrs]
//        -> 8 XCD-private replicas; atomics at WORKGROUP scope so the RMW
//           executes cached in the local XCD L2 (no device-scope write-through)
//   viol[c] = sense==1 ? relu(ax-b) : sense==2 ? relu(b-ax) : |ax-b|
//   out = mean(viol)
// ---------------------------------------------------------------------------

typedef int   i4 __attribute__((ext_vector_type(4)));
typedef float f4 __attribute__((ext_vector_type(4)));

__device__ __forceinline__ float bf16_to_f32(unsigned short u) {
    union { unsigned int i; float f; } cvt;
    cvt.i = ((unsigned int)u) << 16;
    return cvt.f;
}

__device__ __forceinline__ unsigned short f32_to_bf16_rne(float f) {
    union { float f; unsigned int i; } cvt;
    cvt.f = f;
    unsigned int u = cvt.i;
    u += 0x7FFFu + ((u >> 16) & 1u);  // round to nearest even
    return (unsigned short)(u >> 16);
}

// physical XCD id, 0..7 (s_getreg HW_REG_XCC_ID: size=32, offset=0, id=20)
__device__ __forceinline__ int xcc_id() {
    return __builtin_amdgcn_s_getreg((31u << 11) | 20u) & 7;
}

__global__ void sigmoid_kernel(const float* __restrict__ pred,
                               unsigned short* __restrict__ values, int n) {
    int i = blockIdx.x * blockDim.x + threadIdx.x;
    int stride = gridDim.x * blockDim.x;
    int n4 = n >> 2;
    const f4* p4 = (const f4*)pred;
    for (int j = i; j < n4; j += stride) {
        f4 p = p4[j];
        ushort4 o;
        o.x = f32_to_bf16_rne(1.0f / (1.0f + __expf(-p.x)));
        o.y = f32_to_bf16_rne(1.0f / (1.0f + __expf(-p.y)));
        o.z = f32_to_bf16_rne(1.0f / (1.0f + __expf(-p.z)));
        o.w = f32_to_bf16_rne(1.0f / (1.0f + __expf(-p.w)));
        ((ushort4*)values)[j] = o;
    }
    for (int j = (n4 << 2) + i; j < n; j += stride)
        values[j] = f32_to_bf16_rne(1.0f / (1.0f + __expf(-pred[j])));
}

// WEAK==1: XCD-private replica + workgroup-scope atomic (stays in local L2).
// WEAK==0: fallback, device-scope atomic into blockIdx-selected replica.
template <int WEAK>
__global__ void scatter_kernel(const int* __restrict__ cidx,
                               const int* __restrict__ vidx,
                               const float* __restrict__ coeff,
                               const unsigned short* __restrict__ values,
                               float* __restrict__ ax, int nnz,
                               int n_constrs, int kmask) {
    int i = blockIdx.x * blockDim.x + threadIdx.x;
    int stride = gridDim.x * blockDim.x;
    int n4 = nnz >> 2;
    const i4* c4 = (const i4*)cidx;
    const i4* v4 = (const i4*)vidx;
    const f4* w4 = (const f4*)coeff;
    int rep = WEAK ? xcc_id() : (blockIdx.x & kmask);
    float* axr = ax + (size_t)rep * (size_t)n_constrs;
    for (int j = i; j < n4; j += stride) {
        i4 c = __builtin_nontemporal_load(&c4[j]);
        i4 v = __builtin_nontemporal_load(&v4[j]);
        f4 w = __builtin_nontemporal_load(&w4[j]);
        float px = w.x * bf16_to_f32(values[v.x]);
        float py = w.y * bf16_to_f32(values[v.y]);
        float pz = w.z * bf16_to_f32(values[v.z]);
        float pw = w.w * bf16_to_f32(values[v.w]);
        if (WEAK) {
            (void)__hip_atomic_fetch_add(&axr[c.x], px, __ATOMIC_RELAXED, __HIP_MEMORY_SCOPE_WORKGROUP);
            (void)__hip_atomic_fetch_add(&axr[c.y], py, __ATOMIC_RELAXED, __HIP_MEMORY_SCOPE_WORKGROUP);
            (void)__hip_atomic_fetch_add(&axr[c.z], pz, __ATOMIC_RELAXED, __HIP_MEMORY_SCOPE_WORKGROUP);
            (void)__hip_atomic_fetch_add(&axr[c.w], pw, __ATOMIC_RELAXED, __HIP_MEMORY_SCOPE_WORKGROUP);
        } else {
            atomicAdd(&axr[c.x], px);
            atomicAdd(&axr[c.y], py);
            atomicAdd(&axr[c.z], pz);
            atomicAdd(&axr[c.w], pw);
        }
    }
    for (int j = (n4 << 2) + i; j < nnz; j += stride) {
        float p = coeff[j] * bf16_to_f32(values[vidx[j]]);
        if (WEAK)
            (void)__hip_atomic_fetch_add(&axr[cidx[j]], p, __ATOMIC_RELAXED, __HIP_MEMORY_SCOPE_WORKGROUP);
        else
            atomicAdd(&axr[cidx[j]], p);
    }
}

__global__ void combine_reduce_kernel(const float* __restrict__ ax,
                                      const float* __restrict__ rhs,
                                      const int* __restrict__ sense,
                                      float* __restrict__ out,
                                      int n, int nrep, float inv_n) {
    int i = blockIdx.x * blockDim.x + threadIdx.x;
    int stride = gridDim.x * blockDim.x;
    float acc = 0.0f;
    int n4 = n >> 2;
    const f4* r4 = (const f4*)rhs;
    const i4* s4 = (const i4*)sense;
    for (int j = i; j < n4; j += stride) {
        f4 a = ((const f4*)ax)[j];
        for (int r = 1; r < nrep; ++r) {
            f4 b = ((const f4*)(ax + (size_t)r * (size_t)n))[j];
            a.x += b.x; a.y += b.y; a.z += b.z; a.w += b.w;
        }
        f4 rr = r4[j];
        i4 s = s4[j];
        float d;
        d = a.x - rr.x;
        acc += (s.x == 1) ? fmaxf(d, 0.0f) : (s.x == 2) ? fmaxf(-d, 0.0f) : (s.x == 3) ? fabsf(d) : 0.0f;
        d = a.y - rr.y;
        acc += (s.y == 1) ? fmaxf(d, 0.0f) : (s.y == 2) ? fmaxf(-d, 0.0f) : (s.y == 3) ? fabsf(d) : 0.0f;
        d = a.z - rr.z;
        acc += (s.z == 1) ? fmaxf(d, 0.0f) : (s.z == 2) ? fmaxf(-d, 0.0f) : (s.z == 3) ? fabsf(d) : 0.0f;
        d = a.w - rr.w;
        acc += (s.w == 1) ? fmaxf(d, 0.0f) : (s.w == 2) ? fmaxf(-d, 0.0f) : (s.w == 3) ? fabsf(d) : 0.0f;
    }
    for (int j = (n4 << 2) + i; j < n; j += stride) {
        float a = 0.0f;
        for (int r = 0; r < nrep; ++r) a += ax[(size_t)r * (size_t)n + j];
        float d = a - rhs[j];
        int s = sense[j];
        acc += (s == 1) ? fmaxf(d, 0.0f) : (s == 2) ? fmaxf(-d, 0.0f) : (s == 3) ? fabsf(d) : 0.0f;
    }

    for (int off = 32; off > 0; off >>= 1)
        acc += __shfl_down(acc, off, 64);

    __shared__ float lds[8];
    int lane = threadIdx.x & 63;
    int wave = threadIdx.x >> 6;
    if (lane == 0) lds[wave] = acc;
    __syncthreads();
    if (wave == 0) {
        int nwaves = blockDim.x >> 6;
        float b = (lane < nwaves) ? lds[lane] : 0.0f;
        for (int off = 4; off > 0; off >>= 1)
            b += __shfl_down(b, off, 64);
        if (lane == 0) atomicAdd(out, b * inv_n);
    }
}

extern "C" void kernel_launch(void* const* d_in, const int* in_sizes, int n_in,
                              void* d_out, int out_size, void* d_ws, size_t ws_size,
                              hipStream_t stream) {
    const float* pred  = (const float*)d_in[0];
    const int*   cidx  = (const int*)d_in[1];
    const int*   vidx  = (const int*)d_in[2];
    const float* coeff = (const float*)d_in[3];
    const float* rhs   = (const float*)d_in[4];
    const int*   sense = (const int*)d_in[5];

    const int n_vars    = in_sizes[0];
    const int nnz       = in_sizes[1];
    const int n_constrs = in_sizes[4];

    // workspace: values (bf16, n_vars) | ax replicas (K * n_constrs f32)
    unsigned short* values = (unsigned short*)d_ws;
    size_t values_bytes = ((size_t)n_vars * 2 + 255) & ~(size_t)255;
    float* ax = (float*)((char*)d_ws + values_bytes);

    // fast path needs 8 XCD-private replicas
    bool weak = (values_bytes + (size_t)8 * n_constrs * sizeof(float)) <= ws_size;
    int K = 8;
    if (!weak)
        while (K > 1 && values_bytes + (size_t)K * n_constrs * sizeof(float) > ws_size)
            K >>= 1;

    (void)hipMemsetAsync(ax, 0, (size_t)K * n_constrs * sizeof(float), stream);
    (void)hipMemsetAsync(d_out, 0, sizeof(float), stream);

    {
        int threads = 256;
        int blocks = ((n_vars >> 2) + threads - 1) / threads;
        if (blocks < 1) blocks = 1;
        sigmoid_kernel<<<blocks, threads, 0, stream>>>(pred, values, n_vars);
    }
    {
        int threads = 256;
        int blocks = (nnz + threads * 4 - 1) / (threads * 4);
        if (blocks > 8192) blocks = 8192;
        if (blocks < 1) blocks = 1;
        if (weak)
            scatter_kernel<1><<<blocks, threads, 0, stream>>>(
                cidx, vidx, coeff, values, ax, nnz, n_constrs, K - 1);
        else
            scatter_kernel<0><<<blocks, threads, 0, stream>>>(
                cidx, vidx, coeff, values, ax, nnz, n_constrs, K - 1);
    }
    {
        int threads = 256;
        int blocks = ((n_constrs >> 2) + threads - 1) / threads;
        if (blocks > 4096) blocks = 4096;
        if (blocks < 1) blocks = 1;
        combine_reduce_kernel<<<blocks, threads, 0, stream>>>(
            ax, rhs, sense, (float*)d_out, n_constrs, K, 1.0f / (float)n_constrs);
    }
}